// Round 1
// baseline (5629.837 us; speedup 1.0000x reference)
//
#include <hip/hip_runtime.h>
#include <stdint.h>

#define D     512
#define BM    64
#define BN    128
#define BK    64
#define CAND  32
#define MARGIN 1e-3f

typedef __attribute__((ext_vector_type(4))) float f32x4;
typedef __attribute__((ext_vector_type(8))) short s16x8;   // 8 x bf16 bits (4 VGPR)

__device__ __forceinline__ short f2bf(float f) {
  unsigned u = __float_as_uint(f);
  u = (u + 0x7FFFu + ((u >> 16) & 1u)) >> 16;   // RNE fp32 -> bf16
  return (short)u;
}

__device__ __forceinline__ s16x8 pack_bf8(float4 a, float4 b) {
  s16x8 v;
  v[0] = f2bf(a.x); v[1] = f2bf(a.y); v[2] = f2bf(a.z); v[3] = f2bf(a.w);
  v[4] = f2bf(b.x); v[5] = f2bf(b.y); v[6] = f2bf(b.z); v[7] = f2bf(b.w);
  return v;
}

// order-preserving float->uint key (handles negatives); inverse for readback
__device__ __forceinline__ unsigned fkey(float f) {
  unsigned u = __float_as_uint(f);
  return (u >> 31) ? ~u : (u | 0x80000000u);
}
__device__ __forceinline__ float unfkey(unsigned k) {
  unsigned u = (k >> 31) ? (k & 0x7FFFFFFFu) : ~k;
  return __uint_as_float(u);
}

// ---------------- prep: codebook -> bf16, B32[k] = fp32(sum_fp64 of fp32 squares)
__global__ __launch_bounds__(256) void vq_prep(const float* __restrict__ cb,
                                               unsigned short* __restrict__ wh,
                                               float* __restrict__ b32, int K) {
  int wid  = blockIdx.x * 4 + (threadIdx.x >> 6);
  int lane = threadIdx.x & 63;
  if (wid >= K) return;
  const float* row = cb + (size_t)wid * D + lane * 8;
  float4 a = *(const float4*)row;
  float4 b = *(const float4*)(row + 4);
  float v[8] = {a.x, a.y, a.z, a.w, b.x, b.y, b.z, b.w};
  double s = 0.0;
#pragma unroll
  for (int j = 0; j < 8; ++j) { float sq = v[j] * v[j]; s += (double)sq; }
  s16x8 p = pack_bf8(a, b);
  *(s16x8*)((short*)wh + (size_t)wid * D + lane * 8) = p;
#pragma unroll
  for (int m = 1; m < 64; m <<= 1) s += __shfl_xor(s, m);
  if (lane == 0) b32[wid] = (float)s;
}

// ---------------- main: bf16 MFMA screening GEMM + exact fp32-mimic rescore
__global__ __launch_bounds__(512, 1) void vq_main(
    const float* __restrict__ x, const float* __restrict__ cb,
    const unsigned short* __restrict__ wh, const float* __restrict__ b32g,
    float* __restrict__ out_q, float* __restrict__ out_enc, float* __restrict__ out_idx,
    int N, int K) {
  __shared__ short xs[BM * D];            // 64 KiB  x-tile bf16, XOR-swizzled
  __shared__ short wb[2][BN * BK];        // 32 KiB  codebook chunk dbuf, swizzled
  __shared__ unsigned rowmin[BM];
  __shared__ unsigned rowcnt[BM];
  __shared__ unsigned candb[BM][CAND];    // 8 KiB

  const int t    = threadIdx.x;
  const int lane = t & 63;
  const int w    = t >> 6;           // 0..7
  const int wr   = w >> 2;           // 0..1  (row group of 32)
  const int wc   = w & 3;            // 0..3  (col group of 32)
  const int l15  = lane & 15;
  const int l16  = lane >> 4;        // 0..3
  const int m_base = blockIdx.x * BM;
  const int nkt  = K / BN;

  if (t < BM) { rowmin[t] = 0xFFFFFFFFu; rowcnt[t] = 0u; }

  // ---- stage x tile: 64 rows x 512 fp32 -> bf16 swizzled (slot ^= row&7, 16B slots)
  {
    const int r = t >> 3, c0 = (t & 7) * 64;
    const float* src = x + (size_t)(m_base + r) * D + c0;
    short* dst = xs + r * D;
#pragma unroll
    for (int c = 0; c < 64; c += 8) {
      float4 a = *(const float4*)(src + c);
      float4 b = *(const float4*)(src + c + 4);
      int sl = ((c0 + c) >> 3) ^ (r & 7);
      *(s16x8*)(dst + sl * 8) = pack_bf8(a, b);
    }
  }
  __syncthreads();

  const int srow = t >> 2;            // staging: row within BN chunk
  const int ssl  = (t & 3) * 2;       // first 16B slot (of 8 per row)

  for (int kt = 0; kt < nkt; ++kt) {
    f32x4 acc[2][2];
#pragma unroll
    for (int mi = 0; mi < 2; ++mi)
#pragma unroll
      for (int ni = 0; ni < 2; ++ni) acc[mi][ni] = (f32x4){0.f, 0.f, 0.f, 0.f};

    float b32v[2];
#pragma unroll
    for (int ni = 0; ni < 2; ++ni)
      b32v[ni] = b32g[kt * BN + 32 * wc + 16 * ni + l15];

    // prolog: stage chunk 0 (reg -> swizzled LDS)
    {
      const short* g = (const short*)wh + (size_t)(kt * BN + srow) * D + ssl * 8;
      s16x8 v0 = *(const s16x8*)g;
      s16x8 v1 = *(const s16x8*)(g + 8);
      short* p = &wb[0][srow * BK];
      *(s16x8*)(p + ((ssl ^ (srow & 7)) * 8))       = v0;
      *(s16x8*)(p + (((ssl + 1) ^ (srow & 7)) * 8)) = v1;
    }
    __syncthreads();

#pragma unroll
    for (int ds = 0; ds < 8; ++ds) {
      s16x8 n0, n1;
      if (ds < 7) {   // prefetch next chunk into regs (overlaps MFMA below)
        const short* g = (const short*)wh + (size_t)(kt * BN + srow) * D + (ds + 1) * BK + ssl * 8;
        n0 = *(const s16x8*)g;
        n1 = *(const s16x8*)(g + 8);
      }
      const short* wbb = &wb[ds & 1][0];
#pragma unroll
      for (int ks = 0; ks < 2; ++ks) {
        s16x8 af[2], bfr[2];
#pragma unroll
        for (int mi = 0; mi < 2; ++mi) {
          int row = 32 * wr + 16 * mi + l15;
          int sc  = ds * 8 + ks * 4 + l16;
          af[mi] = *(const s16x8*)(xs + row * D + ((sc ^ (row & 7)) * 8));
        }
#pragma unroll
        for (int ni = 0; ni < 2; ++ni) {
          int nn = 32 * wc + 16 * ni + l15;
          int sc = ks * 4 + l16;
          bfr[ni] = *(const s16x8*)(wbb + nn * BK + ((sc ^ (nn & 7)) * 8));
        }
#pragma unroll
        for (int mi = 0; mi < 2; ++mi)
#pragma unroll
          for (int ni = 0; ni < 2; ++ni)
            acc[mi][ni] = __builtin_amdgcn_mfma_f32_16x16x32_bf16(af[mi], bfr[ni], acc[mi][ni], 0, 0, 0);
      }
      if (ds < 7) {
        short* p = &wb[(ds + 1) & 1][srow * BK];
        *(s16x8*)(p + ((ssl ^ (srow & 7)) * 8))       = n0;
        *(s16x8*)(p + (((ssl + 1) ^ (srow & 7)) * 8)) = n1;
      }
      __syncthreads();
    }

    // ---- per-kt epilogue: t = B - 2*dot (approx); row-min + margin candidates
    float tv[2][2][4];
#pragma unroll
    for (int mi = 0; mi < 2; ++mi)
#pragma unroll
      for (int ni = 0; ni < 2; ++ni)
#pragma unroll
        for (int r = 0; r < 4; ++r)
          tv[mi][ni][r] = fmaf(-2.0f, acc[mi][ni][r], b32v[ni]);

#pragma unroll
    for (int mi = 0; mi < 2; ++mi)
#pragma unroll
      for (int r = 0; r < 4; ++r) {
        float m = fminf(tv[mi][0][r], tv[mi][1][r]);
#pragma unroll
        for (int sh = 1; sh < 16; sh <<= 1) m = fminf(m, __shfl_xor(m, sh));
        if (l15 == 0)
          atomicMin(&rowmin[32 * wr + 16 * mi + 4 * l16 + r], fkey(m));
      }
    __syncthreads();

#pragma unroll
    for (int mi = 0; mi < 2; ++mi)
#pragma unroll
      for (int r = 0; r < 4; ++r) {
        const int rl = 32 * wr + 16 * mi + 4 * l16 + r;
        const float thr = unfkey(rowmin[rl]) + MARGIN;
#pragma unroll
        for (int ni = 0; ni < 2; ++ni) {
          if (tv[mi][ni][r] <= thr) {
            unsigned p = atomicAdd(&rowcnt[rl], 1u);
            if (p < CAND) candb[rl][p] = (unsigned)(kt * BN + 32 * wc + 16 * ni + l15);
          }
        }
      }
    __syncthreads();
  }

  // ---- finalize: exact fp32-mimic rescore of candidates, outputs
  for (int r = w; r < BM; r += 8) {
    const int n = m_base + r;
    const float* xr = x + (size_t)n * D + lane * 8;
    float4 xa = *(const float4*)xr;
    float4 xb = *(const float4*)(xr + 4);
    float xv[8] = {xa.x, xa.y, xa.z, xa.w, xb.x, xb.y, xb.z, xb.w};
    double s = 0.0;
#pragma unroll
    for (int j = 0; j < 8; ++j) { float sq = xv[j] * xv[j]; s += (double)sq; }
#pragma unroll
    for (int m = 1; m < 64; m <<= 1) s += __shfl_xor(s, m);
    const float Arow = (float)s;   // fp32(sum x^2), order-invariant for argmin (grid shift)

    const unsigned c = rowcnt[r];
    const bool uselist = (c >= 1u && c <= (unsigned)CAND);
    const int nc = uselist ? (int)c : K;   // overflow => exact full scan (never in practice)
    unsigned long long best = 0xFFFFFFFFFFFFFFFFull;
    for (int i = 0; i < nc; ++i) {
      const int k = uselist ? (int)candb[r][i] : i;
      const float* wp = cb + (size_t)k * D + lane * 8;
      float4 wa = *(const float4*)wp;
      float4 wbv = *(const float4*)(wp + 4);
      float wv[8] = {wa.x, wa.y, wa.z, wa.w, wbv.x, wbv.y, wbv.z, wbv.w};
      double d = 0.0;
#pragma unroll
      for (int j = 0; j < 8; ++j) d += (double)xv[j] * (double)wv[j];
#pragma unroll
      for (int m = 1; m < 64; m <<= 1) d += __shfl_xor(d, m);
      const float C32 = (float)d;                 // fp32(x . w_k)
      const float T1  = Arow + b32g[k];           // fp32(A + B) as reference does
      const float sc  = T1 - 2.0f * C32;          // 2*C32 exact, one rounding
      unsigned long long pk = ((unsigned long long)__float_as_uint(sc) << 32) | (unsigned)k;
      best = best < pk ? best : pk;               // lowest-index tie-break via low bits
    }
    const int kstar = (int)(best & 0xFFFFFFFFu);

    if (lane == 0) {
      out_idx[n] = (float)kstar;
      out_enc[(size_t)n * K + kstar] = 1.0f;
    }
    const float* qs = cb + (size_t)kstar * D + lane * 8;
    float4 q0 = *(const float4*)qs;
    float4 q1 = *(const float4*)(qs + 4);
    float* qd = out_q + (size_t)n * D + lane * 8;
    *(float4*)qd = q0;
    *(float4*)(qd + 4) = q1;
  }
}

extern "C" void kernel_launch(void* const* d_in, const int* in_sizes, int n_in,
                              void* d_out, int out_size, void* d_ws, size_t ws_size,
                              hipStream_t stream) {
  const float* x  = (const float*)d_in[0];
  const float* cb = (const float*)d_in[1];
  const int N = in_sizes[0] / D;
  const int K = in_sizes[1] / D;

  unsigned short* wh = (unsigned short*)d_ws;                       // K*512 bf16 (8 MiB)
  float* b32 = (float*)((char*)d_ws + (size_t)K * D * sizeof(unsigned short));

  float* out     = (float*)d_out;
  float* out_q   = out;
  float* out_enc = out + (size_t)N * D;
  float* out_idx = out + (size_t)N * D + (size_t)N * K;

  hipMemsetAsync(d_out, 0, (size_t)out_size * sizeof(float), stream);
  vq_prep<<<(K + 3) / 4, 256, 0, stream>>>(cb, wh, b32, K);
  vq_main<<<N / BM, 512, 0, stream>>>(x, cb, wh, b32, out_q, out_enc, out_idx, N, K);
}

// Round 2
// 1155.475 us; speedup vs baseline: 4.8723x; 4.8723x over previous
//
#include <hip/hip_runtime.h>
#include <stdint.h>

#define D     512
#define BM    64
#define BN    128
#define BK    64
#define CAND  128
#define MARGIN 5e-4f

typedef __attribute__((ext_vector_type(4))) float f32x4;
typedef __attribute__((ext_vector_type(8))) short s16x8;   // 8 x bf16 bits (4 VGPR)

__device__ __forceinline__ short f2bf(float f) {
  unsigned u = __float_as_uint(f);
  u = (u + 0x7FFFu + ((u >> 16) & 1u)) >> 16;   // RNE fp32 -> bf16
  return (short)u;
}

__device__ __forceinline__ s16x8 pack_bf8(float4 a, float4 b) {
  s16x8 v;
  v[0] = f2bf(a.x); v[1] = f2bf(a.y); v[2] = f2bf(a.z); v[3] = f2bf(a.w);
  v[4] = f2bf(b.x); v[5] = f2bf(b.y); v[6] = f2bf(b.z); v[7] = f2bf(b.w);
  return v;
}

// order-preserving float->uint key (handles negatives); inverse for readback
__device__ __forceinline__ unsigned fkey(float f) {
  unsigned u = __float_as_uint(f);
  return (u >> 31) ? ~u : (u | 0x80000000u);
}
__device__ __forceinline__ float unfkey(unsigned k) {
  unsigned u = (k >> 31) ? (k & 0x7FFFFFFFu) : ~k;
  return __uint_as_float(u);
}

// ---------------- prep: codebook -> bf16, B32[k] = fp32(sum_fp64 of fp32 squares)
__global__ __launch_bounds__(256) void vq_prep(const float* __restrict__ cb,
                                               unsigned short* __restrict__ wh,
                                               float* __restrict__ b32, int K) {
  int wid  = blockIdx.x * 4 + (threadIdx.x >> 6);
  int lane = threadIdx.x & 63;
  if (wid >= K) return;
  const float* row = cb + (size_t)wid * D + lane * 8;
  float4 a = *(const float4*)row;
  float4 b = *(const float4*)(row + 4);
  float v[8] = {a.x, a.y, a.z, a.w, b.x, b.y, b.z, b.w};
  double s = 0.0;
#pragma unroll
  for (int j = 0; j < 8; ++j) { float sq = v[j] * v[j]; s += (double)sq; }
  s16x8 p = pack_bf8(a, b);
  *(s16x8*)((short*)wh + (size_t)wid * D + lane * 8) = p;
#pragma unroll
  for (int m = 1; m < 64; m <<= 1) s += __shfl_xor(s, m);
  if (lane == 0) b32[wid] = (float)s;
}

// ---------------- main: bf16 MFMA screening GEMM + exact fp32-mimic rescore
__global__ __launch_bounds__(512, 1) void vq_main(
    const float* __restrict__ x, const float* __restrict__ cb,
    const unsigned short* __restrict__ wh, const float* __restrict__ b32g,
    float* __restrict__ out_q, float* __restrict__ out_enc, float* __restrict__ out_idx,
    int N, int K) {
  __shared__ short xs[BM * D];            // 64 KiB  x-tile bf16, XOR-swizzled
  __shared__ short wb[2][BN * BK];        // 32 KiB  codebook chunk dbuf, swizzled
  __shared__ unsigned rowmin[BM];
  __shared__ unsigned rowcnt[BM];
  __shared__ unsigned candb[BM][CAND];    // 32 KiB

  const int t    = threadIdx.x;
  const int lane = t & 63;
  const int w    = t >> 6;           // 0..7
  const int wr   = w >> 2;           // 0..1  (row group of 32)
  const int wc   = w & 3;            // 0..3  (col group of 32)
  const int l15  = lane & 15;
  const int l16  = lane >> 4;        // 0..3
  const int m_base = blockIdx.x * BM;
  const int nkt  = K / BN;

  if (t < BM) { rowmin[t] = 0xFFFFFFFFu; rowcnt[t] = 0u; }

  // ---- stage x tile: 64 rows x 512 fp32 -> bf16 swizzled (slot ^= row&7, 16B slots)
  {
    const int r = t >> 3, c0 = (t & 7) * 64;
    const float* src = x + (size_t)(m_base + r) * D + c0;
    short* dst = xs + r * D;
#pragma unroll
    for (int c = 0; c < 64; c += 8) {
      float4 a = *(const float4*)(src + c);
      float4 b = *(const float4*)(src + c + 4);
      int sl = ((c0 + c) >> 3) ^ (r & 7);
      *(s16x8*)(dst + sl * 8) = pack_bf8(a, b);
    }
  }
  __syncthreads();

  const int srow = t >> 2;            // staging: row within BN chunk
  const int ssl  = (t & 3) * 2;       // first 16B slot (of 8 per row)

  for (int kt = 0; kt < nkt; ++kt) {
    f32x4 acc[2][2];
#pragma unroll
    for (int mi = 0; mi < 2; ++mi)
#pragma unroll
      for (int ni = 0; ni < 2; ++ni) acc[mi][ni] = (f32x4){0.f, 0.f, 0.f, 0.f};

    float b32v[2];
#pragma unroll
    for (int ni = 0; ni < 2; ++ni)
      b32v[ni] = b32g[kt * BN + 32 * wc + 16 * ni + l15];

    // prolog: stage chunk 0 (reg -> swizzled LDS)
    {
      const short* g = (const short*)wh + (size_t)(kt * BN + srow) * D + ssl * 8;
      s16x8 v0 = *(const s16x8*)g;
      s16x8 v1 = *(const s16x8*)(g + 8);
      short* p = &wb[0][srow * BK];
      *(s16x8*)(p + ((ssl ^ (srow & 7)) * 8))       = v0;
      *(s16x8*)(p + (((ssl + 1) ^ (srow & 7)) * 8)) = v1;
    }
    __syncthreads();

#pragma unroll
    for (int ds = 0; ds < 8; ++ds) {
      s16x8 n0, n1;
      if (ds < 7) {   // prefetch next chunk into regs (overlaps MFMA below)
        const short* g = (const short*)wh + (size_t)(kt * BN + srow) * D + (ds + 1) * BK + ssl * 8;
        n0 = *(const s16x8*)g;
        n1 = *(const s16x8*)(g + 8);
      }
      const short* wbb = &wb[ds & 1][0];
#pragma unroll
      for (int ks = 0; ks < 2; ++ks) {
        s16x8 af[2], bfr[2];
#pragma unroll
        for (int mi = 0; mi < 2; ++mi) {
          int row = 32 * wr + 16 * mi + l15;
          int sc  = ds * 8 + ks * 4 + l16;
          af[mi] = *(const s16x8*)(xs + row * D + ((sc ^ (row & 7)) * 8));
        }
#pragma unroll
        for (int ni = 0; ni < 2; ++ni) {
          int nn = 32 * wc + 16 * ni + l15;
          int sc = ks * 4 + l16;
          bfr[ni] = *(const s16x8*)(wbb + nn * BK + ((sc ^ (nn & 7)) * 8));
        }
#pragma unroll
        for (int mi = 0; mi < 2; ++mi)
#pragma unroll
          for (int ni = 0; ni < 2; ++ni)
            acc[mi][ni] = __builtin_amdgcn_mfma_f32_16x16x32_bf16(af[mi], bfr[ni], acc[mi][ni], 0, 0, 0);
      }
      if (ds < 7) {
        short* p = &wb[(ds + 1) & 1][srow * BK];
        *(s16x8*)(p + ((ssl ^ (srow & 7)) * 8))       = n0;
        *(s16x8*)(p + (((ssl + 1) ^ (srow & 7)) * 8)) = n1;
      }
      __syncthreads();
    }

    // ---- per-kt epilogue: t = B - 2*dot (approx); row-min + margin candidates.
    // No barriers: rowmin is monotone-decreasing; a racy (stale) read only makes
    // the threshold LOOSER than final-min+MARGIN, never tighter -> the
    // "collect everything within MARGIN of the final min" guarantee holds.
    float tv[2][2][4];
#pragma unroll
    for (int mi = 0; mi < 2; ++mi)
#pragma unroll
      for (int ni = 0; ni < 2; ++ni)
#pragma unroll
        for (int r = 0; r < 4; ++r)
          tv[mi][ni][r] = fmaf(-2.0f, acc[mi][ni][r], b32v[ni]);

#pragma unroll
    for (int mi = 0; mi < 2; ++mi)
#pragma unroll
      for (int r = 0; r < 4; ++r) {
        float m = fminf(tv[mi][0][r], tv[mi][1][r]);
#pragma unroll
        for (int sh = 1; sh < 16; sh <<= 1) m = fminf(m, __shfl_xor(m, sh));
        if (l15 == 0)
          atomicMin(&rowmin[32 * wr + 16 * mi + 4 * l16 + r], fkey(m));
      }

#pragma unroll
    for (int mi = 0; mi < 2; ++mi)
#pragma unroll
      for (int r = 0; r < 4; ++r) {
        const int rl = 32 * wr + 16 * mi + 4 * l16 + r;
        const float thr = unfkey(rowmin[rl]) + MARGIN;
#pragma unroll
        for (int ni = 0; ni < 2; ++ni) {
          if (tv[mi][ni][r] <= thr) {
            unsigned p = atomicAdd(&rowcnt[rl], 1u);
            if (p < CAND) candb[rl][p] = (unsigned)(kt * BN + 32 * wc + 16 * ni + l15);
          }
        }
      }
    __syncthreads();   // protects candb/rowcnt for finalize AND wb[0] restage next kt
  }

  // ---- finalize: exact fp32-mimic rescore of candidates, outputs
  for (int r = w; r < BM; r += 8) {
    const int n = m_base + r;
    const float* xr = x + (size_t)n * D + lane * 8;
    float4 xa = *(const float4*)xr;
    float4 xb = *(const float4*)(xr + 4);
    float xv[8] = {xa.x, xa.y, xa.z, xa.w, xb.x, xb.y, xb.z, xb.w};
    double s = 0.0;
#pragma unroll
    for (int j = 0; j < 8; ++j) { float sq = xv[j] * xv[j]; s += (double)sq; }
#pragma unroll
    for (int m = 1; m < 64; m <<= 1) s += __shfl_xor(s, m);
    const float Arow = (float)s;   // fp32(sum x^2), order-invariant for argmin (grid shift)

    const unsigned c = rowcnt[r];
    const bool uselist = (c >= 1u && c <= (unsigned)CAND);
    const int nc = uselist ? (int)c : K;   // overflow => exact full scan (unreachable at CAND=128)
    unsigned long long best = 0xFFFFFFFFFFFFFFFFull;
    for (int i = 0; i < nc; ++i) {
      const int k = uselist ? (int)candb[r][i] : i;
      const float* wp = cb + (size_t)k * D + lane * 8;
      float4 wa = *(const float4*)wp;
      float4 wbv = *(const float4*)(wp + 4);
      float wv[8] = {wa.x, wa.y, wa.z, wa.w, wbv.x, wbv.y, wbv.z, wbv.w};
      double d = 0.0;
#pragma unroll
      for (int j = 0; j < 8; ++j) d += (double)xv[j] * (double)wv[j];
#pragma unroll
      for (int m = 1; m < 64; m <<= 1) d += __shfl_xor(d, m);
      const float C32 = (float)d;                 // fp32(x . w_k)
      const float T1  = Arow + b32g[k];           // fp32(A + B) as reference does
      const float sc  = T1 - 2.0f * C32;          // 2*C32 exact, one rounding
      unsigned long long pk = ((unsigned long long)__float_as_uint(sc) << 32) | (unsigned)k;
      best = best < pk ? best : pk;               // lowest-index tie-break via low bits
    }
    const int kstar = (int)(best & 0xFFFFFFFFu);

    if (lane == 0) {
      out_idx[n] = (float)kstar;
      out_enc[(size_t)n * K + kstar] = 1.0f;
    }
    const float* qs = cb + (size_t)kstar * D + lane * 8;
    float4 q0 = *(const float4*)qs;
    float4 q1 = *(const float4*)(qs + 4);
    float* qd = out_q + (size_t)n * D + lane * 8;
    *(float4*)qd = q0;
    *(float4*)(qd + 4) = q1;
  }
}

extern "C" void kernel_launch(void* const* d_in, const int* in_sizes, int n_in,
                              void* d_out, int out_size, void* d_ws, size_t ws_size,
                              hipStream_t stream) {
  const float* x  = (const float*)d_in[0];
  const float* cb = (const float*)d_in[1];
  const int N = in_sizes[0] / D;
  const int K = in_sizes[1] / D;

  unsigned short* wh = (unsigned short*)d_ws;                       // K*512 bf16 (8 MiB)
  float* b32 = (float*)((char*)d_ws + (size_t)K * D * sizeof(unsigned short));

  float* out     = (float*)d_out;
  float* out_q   = out;
  float* out_enc = out + (size_t)N * D;
  float* out_idx = out + (size_t)N * D + (size_t)N * K;

  // q and idx are fully overwritten by vq_main; only encodings needs zeroing.
  hipMemsetAsync(out_enc, 0, (size_t)N * (size_t)K * sizeof(float), stream);
  vq_prep<<<(K + 3) / 4, 256, 0, stream>>>(cb, wh, b32, K);
  vq_main<<<N / BM, 512, 0, stream>>>(x, cb, wh, b32, out_q, out_enc, out_idx, N, K);
}

// Round 3
// 732.570 us; speedup vs baseline: 7.6850x; 1.5773x over previous
//
#include <hip/hip_runtime.h>
#include <stdint.h>

#define D     512
#define BM    64
#define BN    128
#define BK    128          // k-elems per chunk; 4 chunks per kt
#define CAND  96
#define MARGIN 5e-4f

typedef __attribute__((ext_vector_type(4))) float f32x4;
typedef __attribute__((ext_vector_type(8))) short s16x8;   // 8 x bf16 bits (4 VGPR)

__device__ __forceinline__ short f2bf(float f) {
  unsigned u = __float_as_uint(f);
  u = (u + 0x7FFFu + ((u >> 16) & 1u)) >> 16;   // RNE fp32 -> bf16
  return (short)u;
}

__device__ __forceinline__ s16x8 pack_bf8(float4 a, float4 b) {
  s16x8 v;
  v[0] = f2bf(a.x); v[1] = f2bf(a.y); v[2] = f2bf(a.z); v[3] = f2bf(a.w);
  v[4] = f2bf(b.x); v[5] = f2bf(b.y); v[6] = f2bf(b.z); v[7] = f2bf(b.w);
  return v;
}

__device__ __forceinline__ unsigned fkey(float f) {
  unsigned u = __float_as_uint(f);
  return (u >> 31) ? ~u : (u | 0x80000000u);
}
__device__ __forceinline__ float unfkey(unsigned k) {
  unsigned u = (k >> 31) ? (k & 0x7FFFFFFFu) : ~k;
  return __uint_as_float(u);
}

// ---------------- prep: codebook -> bf16, B32[k] = fp32(sum_fp64 of fp32 squares)
__global__ __launch_bounds__(256) void vq_prep(const float* __restrict__ cb,
                                               unsigned short* __restrict__ wh,
                                               float* __restrict__ b32, int K) {
  int wid  = blockIdx.x * 4 + (threadIdx.x >> 6);
  int lane = threadIdx.x & 63;
  if (wid >= K) return;
  const float* row = cb + (size_t)wid * D + lane * 8;
  float4 a = *(const float4*)row;
  float4 b = *(const float4*)(row + 4);
  float v[8] = {a.x, a.y, a.z, a.w, b.x, b.y, b.z, b.w};
  double s = 0.0;
#pragma unroll
  for (int j = 0; j < 8; ++j) { float sq = v[j] * v[j]; s += (double)sq; }
  s16x8 p = pack_bf8(a, b);
  *(s16x8*)((short*)wh + (size_t)wid * D + lane * 8) = p;
#pragma unroll
  for (int m = 1; m < 64; m <<= 1) s += __shfl_xor(s, m);
  if (lane == 0) b32[wid] = (float)s;
}

// DMA one 32KB chunk (kt2, c2) into wb[c2]: linear LDS dest, inverse-swizzled
// global source (swizzle: 16B-slot ^= row&15 within each 256B row).
__device__ __forceinline__ void stage4(const unsigned short* __restrict__ wh,
                                       short (*wb)[BN * BK], int kt2, int c2,
                                       int w, int lane) {
#pragma unroll
  for (int i = 0; i < 4; ++i) {
    const int sb  = (w * 4 + i) * 64;     // 16B-slot base for this issue
    const int s   = sb + lane;
    const int row = s >> 4;               // 16 slots per 256B row
    const int sir = s & 15;
    const int ksl = sir ^ (row & 15);     // inverse swizzle on the source
    const unsigned short* src = wh + (size_t)(kt2 * BN + row) * D + c2 * BK + ksl * 8;
    short* dst = &wb[c2][sb * 8];         // wave-uniform base; HW adds lane*16B
    __builtin_amdgcn_global_load_lds(
        (const __attribute__((address_space(1))) unsigned int*)src,
        (__attribute__((address_space(3))) unsigned int*)dst, 16, 0, 0);
  }
}

// ---------------- main: A-in-regs bf16 MFMA screen + exact fp32-mimic rescore
__global__ __launch_bounds__(512, 2) void vq_main(
    const float* __restrict__ x, const float* __restrict__ cb,
    const unsigned short* __restrict__ wh, const float* __restrict__ b32g,
    float* __restrict__ out_q, float* __restrict__ out_enc, float* __restrict__ out_idx,
    int N, int K) {
  __shared__ short wb[4][BN * BK];        // 128 KiB: 4-chunk ring of B tiles
  __shared__ unsigned rowmin[BM];
  __shared__ unsigned rowcnt[BM];
  __shared__ unsigned candb[BM][CAND];    // 24 KiB

  const int t    = threadIdx.x;
  const int lane = t & 63;
  const int w    = t >> 6;           // 0..7
  const int wr   = w >> 2;           // 0..1  row group of 32
  const int wc   = w & 3;            // 0..3  col group of 32
  const int l15  = lane & 15;
  const int l16  = lane >> 4;        // 0..3
  const int m_base = blockIdx.x * BM;
  const int nkt  = K / BN;

  if (t < BM) { rowmin[t] = 0xFFFFFFFFu; rowcnt[t] = 0u; }

  // issue first two chunks of kt=0 while we load A into registers
  stage4(wh, wb, 0, 0, w, lane);
  stage4(wh, wb, 0, 1, w, lane);

  // ---- A fragments resident in registers: afr[mi][f], f = k-step (32 elems)
  s16x8 afr[2][16];
#pragma unroll
  for (int mi = 0; mi < 2; ++mi) {
    const float* xr = x + (size_t)(m_base + 32 * wr + 16 * mi + l15) * D;
#pragma unroll
    for (int f = 0; f < 16; ++f) {
      const float* p = xr + (f * 4 + l16) * 8;
      float4 a = *(const float4*)p;
      float4 b = *(const float4*)(p + 4);
      afr[mi][f] = pack_bf8(a, b);
    }
  }
  __syncthreads();   // drains prologue DMAs + publishes rowmin init

  for (int kt = 0; kt < nkt; ++kt) {
    float b32v[2];
#pragma unroll
    for (int ni = 0; ni < 2; ++ni)
      b32v[ni] = b32g[kt * BN + 32 * wc + 16 * ni + l15];

    f32x4 acc[2][2];
#pragma unroll
    for (int mi = 0; mi < 2; ++mi)
#pragma unroll
      for (int ni = 0; ni < 2; ++ni) acc[mi][ni] = (f32x4){0.f, 0.f, 0.f, 0.f};

#pragma unroll
    for (int c = 0; c < 4; ++c) {
      // issue DMA for chunk g+2 (buffer (c+2)&3; overwrites data read 2 phases ago)
      {
        const int kt2 = kt + ((c + 2) >> 2);
        const int c2  = (c + 2) & 3;
        if (kt2 < nkt) stage4(wh, wb, kt2, c2, w, lane);
      }
      // compute on chunk c (already resident; vmcnt chain guarantees)
      const short* wp = &wb[c][0];
      __builtin_amdgcn_s_setprio(1);
#pragma unroll
      for (int ks = 0; ks < 4; ++ks) {
        s16x8 bfr[2];
#pragma unroll
        for (int ni = 0; ni < 2; ++ni) {
          const int row = 32 * wc + 16 * ni + l15;
          const int sl  = (ks * 4 + l16) ^ (row & 15);
          bfr[ni] = *(const s16x8*)(wp + row * BK + sl * 8);
        }
#pragma unroll
        for (int mi = 0; mi < 2; ++mi)
#pragma unroll
          for (int ni = 0; ni < 2; ++ni)
            acc[mi][ni] = __builtin_amdgcn_mfma_f32_16x16x32_bf16(
                afr[mi][c * 4 + ks], bfr[ni], acc[mi][ni], 0, 0, 0);
      }
      __builtin_amdgcn_s_setprio(0);
      // counted wait: keep newest 4 (chunk g+2) in flight; drain chunk g+1
      if (kt + ((c + 2) >> 2) < nkt) asm volatile("s_waitcnt vmcnt(4)" ::: "memory");
      else                           asm volatile("s_waitcnt vmcnt(0)" ::: "memory");
      __builtin_amdgcn_sched_barrier(0);
      __builtin_amdgcn_s_barrier();
    }

    // ---- epilogue: tv = B - 2*dot (bf16 approx); lazy rowmin + margin collect.
    // rowmin is monotone; stale reads only loosen the threshold -> superset.
    float tv[2][2][4];
#pragma unroll
    for (int mi = 0; mi < 2; ++mi)
#pragma unroll
      for (int ni = 0; ni < 2; ++ni)
#pragma unroll
        for (int r = 0; r < 4; ++r)
          tv[mi][ni][r] = fmaf(-2.0f, acc[mi][ni][r], b32v[ni]);

    if (kt == 0) {   // prime rowmin so the margin test never sees +inf
#pragma unroll
      for (int mi = 0; mi < 2; ++mi)
#pragma unroll
        for (int r = 0; r < 4; ++r)
          atomicMin(&rowmin[32 * wr + 16 * mi + 4 * l16 + r],
                    fkey(fminf(tv[mi][0][r], tv[mi][1][r])));
      __syncthreads();
    }

#pragma unroll
    for (int mi = 0; mi < 2; ++mi) {
      const int rbase = 32 * wr + 16 * mi + 4 * l16;
      const uint4 ru = *(const uint4*)&rowmin[rbase];
      const unsigned rua[4] = {ru.x, ru.y, ru.z, ru.w};
#pragma unroll
      for (int r = 0; r < 4; ++r) {
        const float rm  = unfkey(rua[r]);
        const float thr = rm + MARGIN;
        const float mn  = fminf(tv[mi][0][r], tv[mi][1][r]);
        if (mn < rm) atomicMin(&rowmin[rbase + r], fkey(mn));
#pragma unroll
        for (int ni = 0; ni < 2; ++ni) {
          if (tv[mi][ni][r] <= thr) {
            unsigned p = atomicAdd(&rowcnt[rbase + r], 1u);
            if (p < CAND) candb[rbase + r][p] = (unsigned)(kt * BN + 32 * wc + 16 * ni + l15);
          }
        }
      }
    }
  }
  __syncthreads();

  // ---- finalize: exact fp32-mimic rescore of candidates, outputs
  for (int r = w; r < BM; r += 8) {
    const int n = m_base + r;
    const float* xr = x + (size_t)n * D + lane * 8;
    float4 xa = *(const float4*)xr;
    float4 xb = *(const float4*)(xr + 4);
    float xv[8] = {xa.x, xa.y, xa.z, xa.w, xb.x, xb.y, xb.z, xb.w};
    double s = 0.0;
#pragma unroll
    for (int j = 0; j < 8; ++j) { float sq = xv[j] * xv[j]; s += (double)sq; }
#pragma unroll
    for (int m = 1; m < 64; m <<= 1) s += __shfl_xor(s, m);
    const float Arow = (float)s;   // fp32(sum x^2); order-shift preserves argmin

    const unsigned c = rowcnt[r];
    const bool uselist = (c >= 1u && c <= (unsigned)CAND);
    const int nc = uselist ? (int)c : K;   // overflow => exact full scan (safety net)
    unsigned long long best = 0xFFFFFFFFFFFFFFFFull;
    for (int i = 0; i < nc; ++i) {
      const int k = uselist ? (int)candb[r][i] : i;
      const float* wp = cb + (size_t)k * D + lane * 8;
      float4 wa = *(const float4*)wp;
      float4 wbv = *(const float4*)(wp + 4);
      float wv[8] = {wa.x, wa.y, wa.z, wa.w, wbv.x, wbv.y, wbv.z, wbv.w};
      double d = 0.0;
#pragma unroll
      for (int j = 0; j < 8; ++j) d += (double)xv[j] * (double)wv[j];
#pragma unroll
      for (int m = 1; m < 64; m <<= 1) d += __shfl_xor(d, m);
      const float C32 = (float)d;                 // fp32(x . w_k)
      const float T1  = Arow + b32g[k];           // fp32(A + B) as reference
      const float sc  = T1 - 2.0f * C32;          // one final rounding
      unsigned long long pk = ((unsigned long long)__float_as_uint(sc) << 32) | (unsigned)k;
      best = best < pk ? best : pk;               // lowest-index tie-break
    }
    const int kstar = (int)(best & 0xFFFFFFFFu);

    if (lane == 0) {
      out_idx[n] = (float)kstar;
      out_enc[(size_t)n * K + kstar] = 1.0f;
    }
    const float* qs = cb + (size_t)kstar * D + lane * 8;
    float4 q0 = *(const float4*)qs;
    float4 q1 = *(const float4*)(qs + 4);
    float* qd = out_q + (size_t)n * D + lane * 8;
    *(float4*)qd = q0;
    *(float4*)(qd + 4) = q1;
  }
}

extern "C" void kernel_launch(void* const* d_in, const int* in_sizes, int n_in,
                              void* d_out, int out_size, void* d_ws, size_t ws_size,
                              hipStream_t stream) {
  const float* x  = (const float*)d_in[0];
  const float* cb = (const float*)d_in[1];
  const int N = in_sizes[0] / D;
  const int K = in_sizes[1] / D;

  unsigned short* wh = (unsigned short*)d_ws;                       // K*512 bf16 (8 MiB)
  float* b32 = (float*)((char*)d_ws + (size_t)K * D * sizeof(unsigned short));

  float* out     = (float*)d_out;
  float* out_q   = out;
  float* out_enc = out + (size_t)N * D;
  float* out_idx = out + (size_t)N * D + (size_t)N * K;

  // q and idx are fully overwritten by vq_main; only encodings needs zeroing.
  hipMemsetAsync(out_enc, 0, (size_t)N * (size_t)K * sizeof(float), stream);
  vq_prep<<<(K + 3) / 4, 256, 0, stream>>>(cb, wh, b32, K);
  vq_main<<<N / BM, 512, 0, stream>>>(x, cb, wh, b32, out_q, out_enc, out_idx, N, K);
}

// Round 4
// 572.279 us; speedup vs baseline: 9.8376x; 1.2801x over previous
//
#include <hip/hip_runtime.h>
#include <stdint.h>

#define D     512
#define BM    64
#define BN    128
#define BK    128          // k-elems per chunk; 4 chunks per kt
#define CAND  96
#define MARGIN 5e-4f
#define KDIM  8192

typedef __attribute__((ext_vector_type(4))) float f32x4;
typedef __attribute__((ext_vector_type(8))) short s16x8;   // 8 x bf16 bits (4 VGPR)

__device__ __forceinline__ short f2bf(float f) {
  unsigned u = __float_as_uint(f);
  u = (u + 0x7FFFu + ((u >> 16) & 1u)) >> 16;   // RNE fp32 -> bf16
  return (short)u;
}

__device__ __forceinline__ s16x8 pack_bf8(float4 a, float4 b) {
  s16x8 v;
  v[0] = f2bf(a.x); v[1] = f2bf(a.y); v[2] = f2bf(a.z); v[3] = f2bf(a.w);
  v[4] = f2bf(b.x); v[5] = f2bf(b.y); v[6] = f2bf(b.z); v[7] = f2bf(b.w);
  return v;
}

__device__ __forceinline__ unsigned fkey(float f) {
  unsigned u = __float_as_uint(f);
  return (u >> 31) ? ~u : (u | 0x80000000u);
}
__device__ __forceinline__ float unfkey(unsigned k) {
  unsigned u = (k >> 31) ? (k & 0x7FFFFFFFu) : ~k;
  return __uint_as_float(u);
}

// ---------------- prep: codebook -> bf16, B32[k] = fp32(sum_fp64 of fp32 squares)
__global__ __launch_bounds__(256) void vq_prep(const float* __restrict__ cb,
                                               unsigned short* __restrict__ wh,
                                               float* __restrict__ b32, int K) {
  int wid  = blockIdx.x * 4 + (threadIdx.x >> 6);
  int lane = threadIdx.x & 63;
  if (wid >= K) return;
  const float* row = cb + (size_t)wid * D + lane * 8;
  float4 a = *(const float4*)row;
  float4 b = *(const float4*)(row + 4);
  float v[8] = {a.x, a.y, a.z, a.w, b.x, b.y, b.z, b.w};
  double s = 0.0;
#pragma unroll
  for (int j = 0; j < 8; ++j) { float sq = v[j] * v[j]; s += (double)sq; }
  s16x8 p = pack_bf8(a, b);
  *(s16x8*)((short*)wh + (size_t)wid * D + lane * 8) = p;
#pragma unroll
  for (int m = 1; m < 64; m <<= 1) s += __shfl_xor(s, m);
  if (lane == 0) b32[wid] = (float)s;
}

// DMA one 32KB chunk (kt2, c2) into wb[c2]: linear LDS dest, inverse-swizzled
// global source (swizzle: 16B-slot ^= row&15 within each 256B row).
__device__ __forceinline__ void stage4(const unsigned short* __restrict__ wh,
                                       short (*wb)[BN * BK], int kt2, int c2,
                                       int w, int lane) {
#pragma unroll
  for (int i = 0; i < 4; ++i) {
    const int sb  = (w * 4 + i) * 64;     // 16B-slot base for this issue
    const int s   = sb + lane;
    const int row = s >> 4;               // 16 slots per 256B row
    const int sir = s & 15;
    const int ksl = sir ^ (row & 15);     // inverse swizzle on the source
    const unsigned short* src = wh + (size_t)(kt2 * BN + row) * D + c2 * BK + ksl * 8;
    short* dst = &wb[c2][sb * 8];         // wave-uniform base; HW adds lane*16B
    __builtin_amdgcn_global_load_lds(
        (const __attribute__((address_space(1))) unsigned int*)src,
        (__attribute__((address_space(3))) unsigned int*)dst, 16, 0, 0);
  }
}

// ---------------- main: A-in-regs bf16 MFMA screen + exact fp32-mimic rescore
__global__ __launch_bounds__(512, 2) void vq_main(
    const float* __restrict__ x, const float* __restrict__ cb,
    const unsigned short* __restrict__ wh, const float* __restrict__ b32g,
    float* __restrict__ out_q, float* __restrict__ out_enc, float* __restrict__ out_idx,
    int N, int K) {
  __shared__ short wb[4][BN * BK];        // 128 KiB: 4-chunk ring of B tiles
  __shared__ unsigned rowmin[BM];
  __shared__ unsigned rowcnt[BM];
  __shared__ unsigned candb[BM][CAND];    // 24 KiB

  const int t    = threadIdx.x;
  const int lane = t & 63;
  const int w    = t >> 6;           // 0..7
  const int wr   = w >> 2;           // 0..1  row group of 32
  const int wc   = w & 3;            // 0..3  col group of 32
  const int l15  = lane & 15;
  const int l16  = lane >> 4;        // 0..3
  const int m_base = blockIdx.x * BM;
  const int nkt  = K / BN;
  float* const enc_blk = out_enc + (size_t)m_base * K;   // this block's 2MB slab

  if (t < BM) { rowmin[t] = 0xFFFFFFFFu; rowcnt[t] = 0u; }

  // issue first two chunks of kt=0 while we load A into registers
  stage4(wh, wb, 0, 0, w, lane);
  stage4(wh, wb, 0, 1, w, lane);

  // ---- A fragments resident in registers: afr[mi][f], f = k-step (32 elems)
  s16x8 afr[2][16];
#pragma unroll
  for (int mi = 0; mi < 2; ++mi) {
    const float* xr = x + (size_t)(m_base + 32 * wr + 16 * mi + l15) * D;
#pragma unroll
    for (int f = 0; f < 16; ++f) {
      const float* p = xr + (f * 4 + l16) * 8;
      float4 a = *(const float4*)p;
      float4 b = *(const float4*)(p + 4);
      afr[mi][f] = pack_bf8(a, b);
    }
  }
  __syncthreads();   // drains prologue DMAs + publishes rowmin init

  for (int kt = 0; kt < nkt; ++kt) {
    float b32v[2];
#pragma unroll
    for (int ni = 0; ni < 2; ++ni)
      b32v[ni] = b32g[kt * BN + 32 * wc + 16 * ni + l15];

    f32x4 acc[2][2];
#pragma unroll
    for (int mi = 0; mi < 2; ++mi)
#pragma unroll
      for (int ni = 0; ni < 2; ++ni) acc[mi][ni] = (f32x4){0.f, 0.f, 0.f, 0.f};

#pragma unroll
    for (int c = 0; c < 4; ++c) {
      // issue DMA for chunk g+2 (buffer (c+2)&3; overwrites data read 2 phases ago)
      {
        const int kt2 = kt + ((c + 2) >> 2);
        const int c2  = (c + 2) & 3;
        if (kt2 < nkt) stage4(wh, wb, kt2, c2, w, lane);
      }
      // compute on chunk c (already resident; vmcnt chain guarantees)
      const short* wp = &wb[c][0];
      __builtin_amdgcn_s_setprio(1);
#pragma unroll
      for (int ks = 0; ks < 4; ++ks) {
        s16x8 bfr[2];
#pragma unroll
        for (int ni = 0; ni < 2; ++ni) {
          const int row = 32 * wc + 16 * ni + l15;
          const int sl  = (ks * 4 + l16) ^ (row & 15);
          bfr[ni] = *(const s16x8*)(wp + row * BK + sl * 8);
        }
#pragma unroll
        for (int mi = 0; mi < 2; ++mi)
#pragma unroll
          for (int ni = 0; ni < 2; ++ni)
            acc[mi][ni] = __builtin_amdgcn_mfma_f32_16x16x32_bf16(
                afr[mi][c * 4 + ks], bfr[ni], acc[mi][ni], 0, 0, 0);
      }
      __builtin_amdgcn_s_setprio(0);
      // counted wait: keep newest 4 (chunk g+2) in flight; drain chunk g+1.
      // (epilogue's 4 nt zero-stores are oldest in queue -> also drained, cheap)
      if (kt + ((c + 2) >> 2) < nkt) asm volatile("s_waitcnt vmcnt(4)" ::: "memory");
      else                           asm volatile("s_waitcnt vmcnt(0)" ::: "memory");
      __builtin_amdgcn_sched_barrier(0);
      __builtin_amdgcn_s_barrier();
    }

    // ---- stream 32KB of encodings-zeros for this kt (hides under next kt's MFMA).
    // Zeros are kstar-independent; the 1.0 patch lands in finalize AFTER the
    // final __syncthreads() (vmcnt(0) drain) -> ordered at L2 per-address.
    {
      const f32x4 z4 = {0.f, 0.f, 0.f, 0.f};
      f32x4* ez = (f32x4*)(enc_blk + (size_t)kt * (BM * KDIM / 64));  // 2048 f32x4 per kt
#pragma unroll
      for (int j = 0; j < 4; ++j)
        __builtin_nontemporal_store(z4, ez + j * 512 + t);
    }

    // ---- epilogue: tv = B - 2*dot (bf16 approx); lazy rowmin + margin collect.
    // rowmin is monotone; stale reads only loosen the threshold -> superset.
    float tv[2][2][4];
#pragma unroll
    for (int mi = 0; mi < 2; ++mi)
#pragma unroll
      for (int ni = 0; ni < 2; ++ni)
#pragma unroll
        for (int r = 0; r < 4; ++r)
          tv[mi][ni][r] = fmaf(-2.0f, acc[mi][ni][r], b32v[ni]);

    if (kt == 0) {   // prime rowmin so the margin test never sees +inf
#pragma unroll
      for (int mi = 0; mi < 2; ++mi)
#pragma unroll
        for (int r = 0; r < 4; ++r)
          atomicMin(&rowmin[32 * wr + 16 * mi + 4 * l16 + r],
                    fkey(fminf(tv[mi][0][r], tv[mi][1][r])));
      __syncthreads();
    }

#pragma unroll
    for (int mi = 0; mi < 2; ++mi) {
      const int rbase = 32 * wr + 16 * mi + 4 * l16;
      const uint4 ru = *(const uint4*)&rowmin[rbase];
      const unsigned rua[4] = {ru.x, ru.y, ru.z, ru.w};
#pragma unroll
      for (int r = 0; r < 4; ++r) {
        const float rm  = unfkey(rua[r]);
        const float thr = rm + MARGIN;
        const float mn  = fminf(tv[mi][0][r], tv[mi][1][r]);
        if (mn < rm) atomicMin(&rowmin[rbase + r], fkey(mn));
#pragma unroll
        for (int ni = 0; ni < 2; ++ni) {
          if (tv[mi][ni][r] <= thr) {
            unsigned p = atomicAdd(&rowcnt[rbase + r], 1u);
            if (p < CAND) candb[rbase + r][p] = (unsigned)(kt * BN + 32 * wc + 16 * ni + l15);
          }
        }
      }
    }
  }
  __syncthreads();   // protects candb/rowcnt; drains nt zero-stores (vmcnt(0))

  // ---- finalize: exact fp32-mimic rescore of candidates, outputs
  for (int r = w; r < BM; r += 8) {
    const int n = m_base + r;
    const float* xr = x + (size_t)n * D + lane * 8;
    float4 xa = *(const float4*)xr;
    float4 xb = *(const float4*)(xr + 4);
    float xv[8] = {xa.x, xa.y, xa.z, xa.w, xb.x, xb.y, xb.z, xb.w};
    double s = 0.0;
#pragma unroll
    for (int j = 0; j < 8; ++j) { float sq = xv[j] * xv[j]; s += (double)sq; }
#pragma unroll
    for (int m = 1; m < 64; m <<= 1) s += __shfl_xor(s, m);
    const float Arow = (float)s;   // fp32(sum x^2); order-shift preserves argmin

    const unsigned c = rowcnt[r];
    const bool uselist = (c >= 1u && c <= (unsigned)CAND);
    const int nc = uselist ? (int)c : K;   // overflow => exact full scan (safety net)
    unsigned long long best = 0xFFFFFFFFFFFFFFFFull;
    for (int i = 0; i < nc; ++i) {
      const int k = uselist ? (int)candb[r][i] : i;
      const float* wp = cb + (size_t)k * D + lane * 8;
      float4 wa = *(const float4*)wp;
      float4 wbv = *(const float4*)(wp + 4);
      float wv[8] = {wa.x, wa.y, wa.z, wa.w, wbv.x, wbv.y, wbv.z, wbv.w};
      double d = 0.0;
#pragma unroll
      for (int j = 0; j < 8; ++j) d += (double)xv[j] * (double)wv[j];
#pragma unroll
      for (int m = 1; m < 64; m <<= 1) d += __shfl_xor(d, m);
      const float C32 = (float)d;                 // fp32(x . w_k)
      const float T1  = Arow + b32g[k];           // fp32(A + B) as reference
      const float sc  = T1 - 2.0f * C32;          // one final rounding
      unsigned long long pk = ((unsigned long long)__float_as_uint(sc) << 32) | (unsigned)k;
      best = best < pk ? best : pk;               // lowest-index tie-break
    }
    const int kstar = (int)(best & 0xFFFFFFFFu);

    if (lane == 0) {
      out_idx[n] = (float)kstar;
      out_enc[(size_t)n * K + kstar] = 1.0f;      // patch after zero-drain
    }
    const float* qs = cb + (size_t)kstar * D + lane * 8;
    float4 q0 = *(const float4*)qs;
    float4 q1 = *(const float4*)(qs + 4);
    f32x4* qd = (f32x4*)(out_q + (size_t)n * D + lane * 8);
    f32x4 q0v = {q0.x, q0.y, q0.z, q0.w};
    f32x4 q1v = {q1.x, q1.y, q1.z, q1.w};
    __builtin_nontemporal_store(q0v, qd);
    __builtin_nontemporal_store(q1v, qd + 1);
  }
}

extern "C" void kernel_launch(void* const* d_in, const int* in_sizes, int n_in,
                              void* d_out, int out_size, void* d_ws, size_t ws_size,
                              hipStream_t stream) {
  const float* x  = (const float*)d_in[0];
  const float* cb = (const float*)d_in[1];
  const int N = in_sizes[0] / D;
  const int K = in_sizes[1] / D;

  unsigned short* wh = (unsigned short*)d_ws;                       // K*512 bf16 (8 MiB)
  float* b32 = (float*)((char*)d_ws + (size_t)K * D * sizeof(unsigned short));

  float* out     = (float*)d_out;
  float* out_q   = out;
  float* out_enc = out + (size_t)N * D;
  float* out_idx = out + (size_t)N * D + (size_t)N * K;

  // No memset: vq_main writes the full one-hot rows (zeros + patch) itself.
  vq_prep<<<(K + 3) / 4, 256, 0, stream>>>(cb, wh, b32, K);
  vq_main<<<N / BM, 512, 0, stream>>>(x, cb, wh, b32, out_q, out_enc, out_idx, N, K);
}

// Round 5
// 463.416 us; speedup vs baseline: 12.1486x; 1.2349x over previous
//
#include <hip/hip_runtime.h>
#include <stdint.h>

#define D     512
#define BM    128
#define BN    128
#define BK    128          // k-elems per chunk; 4 chunks per kt
#define CAND  48
#define MARGIN 5e-4f
#define KDIM  8192

typedef __attribute__((ext_vector_type(4))) float f32x4;
typedef __attribute__((ext_vector_type(8))) short s16x8;   // 8 x bf16 bits (4 VGPR)

__device__ __forceinline__ short f2bf(float f) {
  unsigned u = __float_as_uint(f);
  u = (u + 0x7FFFu + ((u >> 16) & 1u)) >> 16;   // RNE fp32 -> bf16
  return (short)u;
}

__device__ __forceinline__ s16x8 pack_bf8(float4 a, float4 b) {
  s16x8 v;
  v[0] = f2bf(a.x); v[1] = f2bf(a.y); v[2] = f2bf(a.z); v[3] = f2bf(a.w);
  v[4] = f2bf(b.x); v[5] = f2bf(b.y); v[6] = f2bf(b.z); v[7] = f2bf(b.w);
  return v;
}

__device__ __forceinline__ unsigned fkey(float f) {
  unsigned u = __float_as_uint(f);
  return (u >> 31) ? ~u : (u | 0x80000000u);
}
__device__ __forceinline__ float unfkey(unsigned k) {
  unsigned u = (k >> 31) ? (k & 0x7FFFFFFFu) : ~k;
  return __uint_as_float(u);
}

// ---------------- prep: codebook -> bf16, B32[k] = fp32(sum_fp64 of fp32 squares)
__global__ __launch_bounds__(256) void vq_prep(const float* __restrict__ cb,
                                               unsigned short* __restrict__ wh,
                                               float* __restrict__ b32, int K) {
  int wid  = blockIdx.x * 4 + (threadIdx.x >> 6);
  int lane = threadIdx.x & 63;
  if (wid >= K) return;
  const float* row = cb + (size_t)wid * D + lane * 8;
  float4 a = *(const float4*)row;
  float4 b = *(const float4*)(row + 4);
  float v[8] = {a.x, a.y, a.z, a.w, b.x, b.y, b.z, b.w};
  double s = 0.0;
#pragma unroll
  for (int j = 0; j < 8; ++j) { float sq = v[j] * v[j]; s += (double)sq; }
  s16x8 p = pack_bf8(a, b);
  *(s16x8*)((short*)wh + (size_t)wid * D + lane * 8) = p;
#pragma unroll
  for (int m = 1; m < 64; m <<= 1) s += __shfl_xor(s, m);
  if (lane == 0) b32[wid] = (float)s;
}

// DMA one 32KB chunk (kt2, c2) into wb[c2]: linear LDS dest, inverse-swizzled
// global source (swizzle: 16B-slot ^= row&15 within each 256B row).
__device__ __forceinline__ void stage4(const unsigned short* __restrict__ wh,
                                       short (*wb)[BN * BK], int kt2, int c2,
                                       int w, int lane) {
#pragma unroll
  for (int i = 0; i < 4; ++i) {
    const int sb  = (w * 4 + i) * 64;     // 16B-slot base for this issue
    const int s   = sb + lane;
    const int row = s >> 4;               // 16 slots per 256B row
    const int sir = s & 15;
    const int ksl = sir ^ (row & 15);     // inverse swizzle on the source
    const unsigned short* src = wh + (size_t)(kt2 * BN + row) * D + c2 * BK + ksl * 8;
    short* dst = &wb[c2][sb * 8];         // wave-uniform base; HW adds lane*16B
    __builtin_amdgcn_global_load_lds(
        (const __attribute__((address_space(1))) unsigned int*)src,
        (__attribute__((address_space(3))) unsigned int*)dst, 16, 0, 0);
  }
}

// ---------------- main: A-in-regs bf16 MFMA screen + exact fp32-mimic rescore
// BM=128, 1 block/CU, wave grid 4(row-groups of 32) x 2(col-groups of 64).
__global__ __launch_bounds__(512, 2) void vq_main(
    const float* __restrict__ x, const float* __restrict__ cb,
    const unsigned short* __restrict__ wh, const float* __restrict__ b32g,
    float* __restrict__ out_q, float* __restrict__ out_enc, float* __restrict__ out_idx,
    int N, int K) {
  __shared__ short wb[4][BN * BK];        // 128 KiB: 4-chunk ring of B tiles
  __shared__ unsigned rowmin[BM];
  __shared__ unsigned rowcnt[BM];
  __shared__ unsigned candb[BM][CAND];    // 24 KiB

  const int t    = threadIdx.x;
  const int lane = t & 63;
  const int w    = t >> 6;           // 0..7
  const int wr   = w >> 1;           // 0..3  row group of 32
  const int wc   = w & 1;            // 0..1  col group of 64
  const int l15  = lane & 15;
  const int l16  = lane >> 4;        // 0..3
  const int m_base = blockIdx.x * BM;
  const int nkt  = K / BN;
  float* const enc_blk = out_enc + (size_t)m_base * K;   // this block's 4MB slab

  if (t < BM) { rowmin[t] = 0xFFFFFFFFu; rowcnt[t] = 0u; }

  // issue first two chunks of kt=0 while we load A into registers
  stage4(wh, wb, 0, 0, w, lane);
  stage4(wh, wb, 0, 1, w, lane);

  // ---- A fragments resident in registers: afr[mi][f], f = k-step (32 elems)
  s16x8 afr[2][16];
#pragma unroll
  for (int mi = 0; mi < 2; ++mi) {
    const float* xr = x + (size_t)(m_base + 32 * wr + 16 * mi + l15) * D;
#pragma unroll
    for (int f = 0; f < 16; ++f) {
      const float* p = xr + (f * 4 + l16) * 8;
      float4 a = *(const float4*)p;
      float4 b = *(const float4*)(p + 4);
      afr[mi][f] = pack_bf8(a, b);
    }
  }
  __syncthreads();   // drains prologue DMAs + publishes rowmin init

  for (int kt = 0; kt < nkt; ++kt) {
    float b32v[4];
#pragma unroll
    for (int ni = 0; ni < 4; ++ni)
      b32v[ni] = b32g[kt * BN + 64 * wc + 16 * ni + l15];

    f32x4 acc[2][4];
#pragma unroll
    for (int mi = 0; mi < 2; ++mi)
#pragma unroll
      for (int ni = 0; ni < 4; ++ni) acc[mi][ni] = (f32x4){0.f, 0.f, 0.f, 0.f};

#pragma unroll
    for (int c = 0; c < 4; ++c) {
      // 2 encodings-zero stores FIRST (older than the prefetch in vmcnt queue;
      // drained by this phase's vmcnt(4) after a full MFMA phase of slack)
      {
        const f32x4 z4 = {0.f, 0.f, 0.f, 0.f};
        f32x4* ez = (f32x4*)(enc_blk + (size_t)kt * (BM * KDIM / 64));
        __builtin_nontemporal_store(z4, ez + (c * 2 + 0) * 512 + t);
        __builtin_nontemporal_store(z4, ez + (c * 2 + 1) * 512 + t);
      }
      // issue DMA for chunk g+2 (buffer (c+2)&3; its readers finished 2 barriers ago)
      const int kt2 = kt + ((c + 2) >> 2);
      if (kt2 < nkt) stage4(wh, wb, kt2, (c + 2) & 3, w, lane);

      // compute on chunk c (resident; vmcnt chain guarantees)
      const short* wp = &wb[c][0];
      __builtin_amdgcn_s_setprio(1);
#pragma unroll
      for (int ks = 0; ks < 4; ++ks) {
        s16x8 bfr[4];
#pragma unroll
        for (int ni = 0; ni < 4; ++ni) {
          const int row = 64 * wc + 16 * ni + l15;
          const int sl  = (ks * 4 + l16) ^ (row & 15);
          bfr[ni] = *(const s16x8*)(wp + row * BK + sl * 8);
        }
#pragma unroll
        for (int mi = 0; mi < 2; ++mi)
#pragma unroll
          for (int ni = 0; ni < 4; ++ni)
            acc[mi][ni] = __builtin_amdgcn_mfma_f32_16x16x32_bf16(
                afr[mi][c * 4 + ks], bfr[ni], acc[mi][ni], 0, 0, 0);
      }
      __builtin_amdgcn_s_setprio(0);
      // counted wait: keep newest 4 (chunk g+2 DMA) in flight; drains chunk g+1
      // DMA and this phase's 2 stores (both older than the g+2 issues).
      if (kt2 < nkt) asm volatile("s_waitcnt vmcnt(4)" ::: "memory");
      else           asm volatile("s_waitcnt vmcnt(0)" ::: "memory");
      __builtin_amdgcn_sched_barrier(0);
      __builtin_amdgcn_s_barrier();
    }

    // ---- epilogue: tv = B - 2*dot (bf16 approx); lazy rowmin + margin collect.
    // rowmin is monotone; stale reads only loosen the threshold -> superset.
    float tv[2][4][4];
#pragma unroll
    for (int mi = 0; mi < 2; ++mi)
#pragma unroll
      for (int ni = 0; ni < 4; ++ni)
#pragma unroll
        for (int r = 0; r < 4; ++r)
          tv[mi][ni][r] = fmaf(-2.0f, acc[mi][ni][r], b32v[ni]);

    if (kt == 0) {   // prime rowmin so the margin test never sees +inf
#pragma unroll
      for (int mi = 0; mi < 2; ++mi)
#pragma unroll
        for (int r = 0; r < 4; ++r) {
          float m = fminf(fminf(tv[mi][0][r], tv[mi][1][r]),
                          fminf(tv[mi][2][r], tv[mi][3][r]));
          atomicMin(&rowmin[32 * wr + 16 * mi + 4 * l16 + r], fkey(m));
        }
      __syncthreads();
    }

#pragma unroll
    for (int mi = 0; mi < 2; ++mi) {
      const int rbase = 32 * wr + 16 * mi + 4 * l16;
      const uint4 ru = *(const uint4*)&rowmin[rbase];
      const unsigned rua[4] = {ru.x, ru.y, ru.z, ru.w};
#pragma unroll
      for (int r = 0; r < 4; ++r) {
        const float rm  = unfkey(rua[r]);
        const float thr = rm + MARGIN;
        const float mn  = fminf(fminf(tv[mi][0][r], tv[mi][1][r]),
                                fminf(tv[mi][2][r], tv[mi][3][r]));
        if (mn < rm) atomicMin(&rowmin[rbase + r], fkey(mn));
#pragma unroll
        for (int ni = 0; ni < 4; ++ni) {
          if (tv[mi][ni][r] <= thr) {
            unsigned p = atomicAdd(&rowcnt[rbase + r], 1u);
            if (p < CAND) candb[rbase + r][p] = (unsigned)(kt * BN + 64 * wc + 16 * ni + l15);
          }
        }
      }
    }
  }
  __syncthreads();   // protects candb/rowcnt; drains last nt zero-stores

  // ---- finalize: exact fp32-mimic rescore of candidates, outputs
  for (int r = w; r < BM; r += 8) {
    const int n = m_base + r;
    const float* xr = x + (size_t)n * D + lane * 8;
    float4 xa = *(const float4*)xr;
    float4 xb = *(const float4*)(xr + 4);
    float xv[8] = {xa.x, xa.y, xa.z, xa.w, xb.x, xb.y, xb.z, xb.w};
    double s = 0.0;
#pragma unroll
    for (int j = 0; j < 8; ++j) { float sq = xv[j] * xv[j]; s += (double)sq; }
#pragma unroll
    for (int m = 1; m < 64; m <<= 1) s += __shfl_xor(s, m);
    const float Arow = (float)s;   // fp32(sum x^2); grid-shift preserves argmin

    const unsigned c = rowcnt[r];
    const bool uselist = (c >= 1u && c <= (unsigned)CAND);
    const int nc = uselist ? (int)c : K;   // overflow => exact full scan (safety net)
    unsigned long long best = 0xFFFFFFFFFFFFFFFFull;
    for (int i = 0; i < nc; ++i) {
      const int k = uselist ? (int)candb[r][i] : i;
      const float* wp = cb + (size_t)k * D + lane * 8;
      float4 wa = *(const float4*)wp;
      float4 wbv = *(const float4*)(wp + 4);
      float wv[8] = {wa.x, wa.y, wa.z, wa.w, wbv.x, wbv.y, wbv.z, wbv.w};
      double d = 0.0;
#pragma unroll
      for (int j = 0; j < 8; ++j) d += (double)xv[j] * (double)wv[j];
#pragma unroll
      for (int m = 1; m < 64; m <<= 1) d += __shfl_xor(d, m);
      const float C32 = (float)d;                 // fp32(x . w_k)
      const float T1  = Arow + b32g[k];           // fp32(A + B) as reference
      const float sc  = T1 - 2.0f * C32;          // one final rounding
      unsigned long long pk = ((unsigned long long)__float_as_uint(sc) << 32) | (unsigned)k;
      best = best < pk ? best : pk;               // lowest-index tie-break
    }
    const int kstar = (int)(best & 0xFFFFFFFFu);

    if (lane == 0) {
      out_idx[n] = (float)kstar;
      out_enc[(size_t)n * K + kstar] = 1.0f;      // patch after zero-drain
    }
    const float* qs = cb + (size_t)kstar * D + lane * 8;
    float4 q0 = *(const float4*)qs;
    float4 q1 = *(const float4*)(qs + 4);
    f32x4* qd = (f32x4*)(out_q + (size_t)n * D + lane * 8);
    f32x4 q0v = {q0.x, q0.y, q0.z, q0.w};
    f32x4 q1v = {q1.x, q1.y, q1.z, q1.w};
    __builtin_nontemporal_store(q0v, qd);
    __builtin_nontemporal_store(q1v, qd + 1);
  }
}

extern "C" void kernel_launch(void* const* d_in, const int* in_sizes, int n_in,
                              void* d_out, int out_size, void* d_ws, size_t ws_size,
                              hipStream_t stream) {
  const float* x  = (const float*)d_in[0];
  const float* cb = (const float*)d_in[1];
  const int N = in_sizes[0] / D;
  const int K = in_sizes[1] / D;

  unsigned short* wh = (unsigned short*)d_ws;                       // K*512 bf16 (8 MiB)
  float* b32 = (float*)((char*)d_ws + (size_t)K * D * sizeof(unsigned short));

  float* out     = (float*)d_out;
  float* out_q   = out;
  float* out_enc = out + (size_t)N * D;
  float* out_idx = out + (size_t)N * D + (size_t)N * K;

  // No memset: vq_main writes the full one-hot rows (zeros + patch) itself.
  vq_prep<<<(K + 3) / 4, 256, 0, stream>>>(cb, wh, b32, K);
  vq_main<<<N / BM, 512, 0, stream>>>(x, cb, wh, b32, out_q, out_enc, out_idx, N, K);
}